// Round 1
// baseline (926.325 us; speedup 1.0000x reference)
//
#include <hip/hip_runtime.h>
#include <stdint.h>

// ---------------------------------------------------------------------------
// CausalSelfAttention with LoRA(Q,K) + RoPE, bf16 MFMA pipeline for gfx950.
// B=4, T=2048, C=2048, H=16, D=128, LORA_R=8.
// ---------------------------------------------------------------------------

typedef __attribute__((ext_vector_type(8))) short short8;
typedef __attribute__((ext_vector_type(4))) float floatx4;

__device__ __forceinline__ float bf2f(short h) {
  union { unsigned int u; float f; } v;
  v.u = ((unsigned int)(unsigned short)h) << 16;
  return v.f;
}
__device__ __forceinline__ short f2bf(float f) {
  unsigned int u = __float_as_uint(f);
  unsigned int r = (u + 0x7FFFu + ((u >> 16) & 1u)) >> 16;  // RNE
  return (short)r;
}

__device__ __forceinline__ void gload_lds16(const short* g, short* l) {
  __builtin_amdgcn_global_load_lds(
      (const __attribute__((address_space(1))) unsigned int*)g,
      (__attribute__((address_space(3))) unsigned int*)l, 16, 0, 0);
}

__device__ __forceinline__ void store_out(float* p, float v) { *p = v; }
__device__ __forceinline__ void store_out(short* p, float v) { *p = f2bf(v); }

// ---------------- fp32 -> bf16 convert (vectorized) ----------------
__global__ void k_f2b(const float* __restrict__ in, short* __restrict__ out, int n8) {
  int i = blockIdx.x * 256 + threadIdx.x;
  if (i >= n8) return;
  const float4* p = (const float4*)in + (size_t)i * 2;
  float4 a = p[0], b = p[1];
  short8 v;
  v[0] = f2bf(a.x); v[1] = f2bf(a.y); v[2] = f2bf(a.z); v[3] = f2bf(a.w);
  v[4] = f2bf(b.x); v[5] = f2bf(b.y); v[6] = f2bf(b.z); v[7] = f2bf(b.w);
  *(short8*)(out + (size_t)i * 8) = v;
}

// ---------------- W [K][N] fp32 -> WT [N][K] bf16 (tiled transpose) ----------------
__global__ void k_wT(const float* __restrict__ W, short* __restrict__ WT, int K, int N) {
  __shared__ float tile[32][33];
  int n0 = blockIdx.x * 32, k0 = blockIdx.y * 32;
  int tx = threadIdx.x, ty = threadIdx.y;  // (32,8)
  #pragma unroll
  for (int i = 0; i < 4; i++)
    tile[ty + i * 8][tx] = W[(size_t)(k0 + ty + i * 8) * N + n0 + tx];
  __syncthreads();
  #pragma unroll
  for (int i = 0; i < 4; i++)
    WT[(size_t)(n0 + ty + i * 8) * K + k0 + tx] = f2bf(tile[tx][ty + i * 8]);
}

// ---------------- RoPE cos/sin tables [2048][64] fp32 ----------------
__global__ void k_ropetab(float* __restrict__ ct, float* __restrict__ st) {
  int t = blockIdx.x, j = threadIdx.x;  // 64 threads
  float invf = powf(10000.0f, -(float)(2 * j) / 128.0f);
  float ang = (float)t * invf;
  ct[t * 64 + j] = cosf(ang);
  st[t * 64 + j] = sinf(ang);
}

// ---------------- bf16 MFMA GEMM: C[M][N] = A[M][K] @ BT[N][K]^T + bias ----------------
// 128x128 tile, BK=64, 4 waves, each wave 64x64 (4x4 frags of 16x16x32).
template <typename OutT>
__global__ __launch_bounds__(256, 2) void k_gemm(
    const short* __restrict__ A, const short* __restrict__ BT,
    const float* __restrict__ bias, OutT* __restrict__ C,
    int M, int N, int K)
{
  __shared__ __attribute__((aligned(16))) short As[128 * 64];
  __shared__ __attribute__((aligned(16))) short Bs[128 * 64];
  const int t = threadIdx.x;
  const int w = t >> 6, l = t & 63;
  const int g = l >> 4, c16 = l & 15;
  const int lr = l >> 3, lc8 = (l & 7) * 8;
  const int wr = w >> 1, wc = w & 1;
  const size_t bm = blockIdx.x, bn = blockIdx.y;

  floatx4 acc[4][4];
  #pragma unroll
  for (int m = 0; m < 4; m++)
    #pragma unroll
    for (int n = 0; n < 4; n++)
      acc[m][n] = (floatx4){0.f, 0.f, 0.f, 0.f};

  const short* Ablk = A + bm * 128 * (size_t)K;
  const short* Bblk = BT + bn * 128 * (size_t)K;

  for (int k0 = 0; k0 < K; k0 += 64) {
    #pragma unroll
    for (int i = 0; i < 4; i++) {
      int row = (i * 4 + w) * 8 + lr;  // per-wave-contiguous LDS chunks
      gload_lds16(Ablk + (size_t)row * K + k0 + lc8, As + row * 64 + lc8);
      gload_lds16(Bblk + (size_t)row * K + k0 + lc8, Bs + row * 64 + lc8);
    }
    __syncthreads();
    #pragma unroll
    for (int kk = 0; kk < 64; kk += 32) {
      short8 af[4], bfv[4];
      #pragma unroll
      for (int m = 0; m < 4; m++)
        af[m] = *(const short8*)(As + (wr * 64 + m * 16 + c16) * 64 + kk + 8 * g);
      #pragma unroll
      for (int n = 0; n < 4; n++)
        bfv[n] = *(const short8*)(Bs + (wc * 64 + n * 16 + c16) * 64 + kk + 8 * g);
      #pragma unroll
      for (int m = 0; m < 4; m++)
        #pragma unroll
        for (int n = 0; n < 4; n++)
          acc[m][n] = __builtin_amdgcn_mfma_f32_16x16x32_bf16(af[m], bfv[n], acc[m][n], 0, 0, 0);
    }
    __syncthreads();
  }

  #pragma unroll
  for (int m = 0; m < 4; m++) {
    #pragma unroll
    for (int n = 0; n < 4; n++) {
      int col = (int)bn * 128 + wc * 64 + n * 16 + c16;
      float bv = bias[col];
      #pragma unroll
      for (int r = 0; r < 4; r++) {
        size_t rowg = bm * 128 + (size_t)(wr * 64 + m * 16 + g * 4 + r);
        store_out(C + rowg * (size_t)N + col, acc[m][n][r] + bv);
      }
    }
  }
}

// ---------------- LoRA stage 1: T[row][8] = qkv_slice[row][:2048] @ A ----------------
__global__ __launch_bounds__(256) void k_lora_t(
    const short* __restrict__ qkv, const float* __restrict__ Aq,
    const float* __restrict__ Ak, float* __restrict__ Tq, float* __restrict__ Tk)
{
  const int row = blockIdx.x, which = blockIdx.y;
  const float* Am = which ? Ak : Aq;
  float* T = which ? Tk : Tq;
  const short* src = qkv + (size_t)row * 6144 + which * 2048;
  const int t = threadIdx.x;
  short8 q8 = *(const short8*)(src + t * 8);
  float acc[8];
  #pragma unroll
  for (int r = 0; r < 8; r++) acc[r] = 0.f;
  #pragma unroll
  for (int e = 0; e < 8; e++) {
    float qv = bf2f(q8[e]);
    const float* ar = Am + (size_t)(t * 8 + e) * 8;
    #pragma unroll
    for (int r = 0; r < 8; r++) acc[r] += qv * ar[r];
  }
  #pragma unroll
  for (int r = 0; r < 8; r++)
    for (int off = 32; off > 0; off >>= 1)
      acc[r] += __shfl_xor(acc[r], off);
  __shared__ float red[4][8];
  int w = t >> 6, l = t & 63;
  if (l == 0) {
    #pragma unroll
    for (int r = 0; r < 8; r++) red[w][r] = acc[r];
  }
  __syncthreads();
  if (t < 8)
    T[(size_t)row * 8 + t] = red[0][t] + red[1][t] + red[2][t] + red[3][t];
}

// lora'd value at column c of a 2048-wide q/k row
__device__ __forceinline__ float lval(const short* row, const float* Bm,
                                      const float* Tr, int c) {
  float v = bf2f(row[c]);
  #pragma unroll
  for (int r = 0; r < 8; r++) v += Tr[r] * Bm[r * 2048 + c];
  return v;
}

// ---------------- LoRA delta + RoPE (+1/sqrt(D) fold on q), in-place ----------------
__global__ __launch_bounds__(256) void k_finalize(
    short* __restrict__ qkv, const float* __restrict__ Tq, const float* __restrict__ Tk,
    const float* __restrict__ Bq, const float* __restrict__ Bk,
    const float* __restrict__ ct, const float* __restrict__ st)
{
  const int tok = blockIdx.x, which = blockIdx.y;
  const float* Bm = which ? Bk : Bq;
  const float* T = (which ? Tk : Tq) + (size_t)tok * 8;
  short* row = qkv + (size_t)tok * 6144 + which * 2048;
  const int trow = tok & 2047;
  float Tr[8];
  #pragma unroll
  for (int r = 0; r < 8; r++) Tr[r] = T[r] * 0.125f;  // LORA_SCALING = 1/8
  const float qs = which ? 1.0f : 0.08838834764831845f;  // 1/sqrt(128) folded into q
  const int tid = threadIdx.x;
  float o1[4], o2[4];
  #pragma unroll
  for (int i = 0; i < 4; i++) {
    int u = tid + i * 256;
    int h = u >> 6, j = u & 63;
    int base = h * 128;
    // rope: out[j] = q[j]*cos - q[2j+1]*sin ; out[j+64] = q[j+64]*cos + q[2j]*sin
    float qa = lval(row, Bm, Tr, base + j);
    float qb = lval(row, Bm, Tr, base + j + 64);
    float qe = lval(row, Bm, Tr, base + 2 * j);
    float qo = lval(row, Bm, Tr, base + 2 * j + 1);
    float c = ct[trow * 64 + j], s = st[trow * 64 + j];
    o1[i] = (qa * c - qo * s) * qs;
    o2[i] = (qb * c + qe * s) * qs;
  }
  __syncthreads();  // all reads complete before in-place writes
  #pragma unroll
  for (int i = 0; i < 4; i++) {
    int u = tid + i * 256;
    int h = u >> 6, j = u & 63;
    int base = h * 128;
    row[base + j] = f2bf(o1[i]);
    row[base + j + 64] = f2bf(o2[i]);
  }
}

// ---------------- V transpose: vT[bh][d][t] = qkv[b*2048+t][4096 + h*128 + d] ----------------
__global__ void k_vt(const short* __restrict__ qkv, short* __restrict__ vT) {
  __shared__ short tile[32][33];
  int bh = blockIdx.z, b = bh >> 4, h = bh & 15;
  int t0 = blockIdx.x * 32, d0 = blockIdx.y * 32;
  int tx = threadIdx.x, ty = threadIdx.y;  // (32,8)
  #pragma unroll
  for (int i = 0; i < 4; i++) {
    int tt = t0 + ty + i * 8;
    tile[ty + i * 8][tx] = qkv[(size_t)(b * 2048 + tt) * 6144 + 4096 + h * 128 + d0 + tx];
  }
  __syncthreads();
  #pragma unroll
  for (int i = 0; i < 4; i++) {
    int d = d0 + ty + i * 8;
    vT[((size_t)bh * 128 + d) * 2048 + t0 + tx] = tile[tx][ty + i * 8];
  }
}

// ---------------- causal flash attention ----------------
// grid (T/64, B*H); block 256 = 4 waves, each wave owns 16 q-rows.
__global__ __launch_bounds__(256, 2) void k_attn(
    const short* __restrict__ qkv, const short* __restrict__ vT, short* __restrict__ y)
{
  __shared__ __attribute__((aligned(16))) short Ks[64 * 136];   // padded: stride 136
  __shared__ __attribute__((aligned(16))) short Vs[128 * 72];   // padded: stride 72
  __shared__ __attribute__((aligned(16))) short Ps[4 * 16 * 72];
  const int qt = blockIdx.x, bh = blockIdx.y, b = bh >> 4, h = bh & 15;
  const int t = threadIdx.x, w = t >> 6, l = t & 63, g = l >> 4, c16 = l & 15;

  short8 qf[4];  // Q A-fragments, row = c16, k = kf*32 + 8g + e
  {
    size_t goff = (size_t)(b * 2048 + qt * 64 + w * 16 + c16) * 6144 + h * 128;
    #pragma unroll
    for (int kf = 0; kf < 4; kf++)
      qf[kf] = *(const short8*)(qkv + goff + kf * 32 + 8 * g);
  }

  floatx4 o[8];
  #pragma unroll
  for (int nf = 0; nf < 8; nf++) o[nf] = (floatx4){0.f, 0.f, 0.f, 0.f};
  float mrow[4] = {-1e30f, -1e30f, -1e30f, -1e30f};
  float lrow[4] = {0.f, 0.f, 0.f, 0.f};

  const int skr = t >> 2, sc0 = (t & 3) * 32;   // K staging: row, col base
  const int svd = t >> 1, sv0 = (t & 1) * 32;   // V staging
  const short* kbase = qkv + (size_t)(b * 2048) * 6144 + 2048 + h * 128;
  const short* vbase = vT + (size_t)bh * 128 * 2048;
  short* Pw = Ps + w * (16 * 72);

  for (int kt = 0; kt <= qt; kt++) {
    __syncthreads();  // previous iter's LDS reads done
    #pragma unroll
    for (int ii = 0; ii < 4; ii++) {
      short8 kv = *(const short8*)(kbase + (size_t)(kt * 64 + skr) * 6144 + sc0 + ii * 8);
      *(short8*)(Ks + skr * 136 + sc0 + ii * 8) = kv;
    }
    #pragma unroll
    for (int ii = 0; ii < 4; ii++) {
      short8 vv = *(const short8*)(vbase + (size_t)svd * 2048 + kt * 64 + sv0 + ii * 8);
      *(short8*)(Vs + svd * 72 + sv0 + ii * 8) = vv;
    }
    __syncthreads();  // staged tiles visible

    floatx4 sc[4];
    #pragma unroll
    for (int nf = 0; nf < 4; nf++) sc[nf] = (floatx4){0.f, 0.f, 0.f, 0.f};
    #pragma unroll
    for (int nf = 0; nf < 4; nf++)
      #pragma unroll
      for (int kf = 0; kf < 4; kf++) {
        short8 kb = *(const short8*)(Ks + (nf * 16 + c16) * 136 + kf * 32 + 8 * g);
        sc[nf] = __builtin_amdgcn_mfma_f32_16x16x32_bf16(qf[kf], kb, sc[nf], 0, 0, 0);
      }

    if (kt == qt) {  // diagonal tile: causal mask
      #pragma unroll
      for (int nf = 0; nf < 4; nf++) {
        int key = kt * 64 + nf * 16 + c16;
        #pragma unroll
        for (int r = 0; r < 4; r++) {
          int qr = qt * 64 + w * 16 + g * 4 + r;
          if (key > qr) sc[nf][r] = -1e30f;
        }
      }
    }

    // online softmax (rows live in 16-lane groups; regs r = 4 rows per lane)
    float pv[4][4];
    #pragma unroll
    for (int r = 0; r < 4; r++) {
      float rm = fmaxf(fmaxf(sc[0][r], sc[1][r]), fmaxf(sc[2][r], sc[3][r]));
      rm = fmaxf(rm, __shfl_xor(rm, 1));
      rm = fmaxf(rm, __shfl_xor(rm, 2));
      rm = fmaxf(rm, __shfl_xor(rm, 4));
      rm = fmaxf(rm, __shfl_xor(rm, 8));
      float mn = fmaxf(mrow[r], rm);
      float al = __expf(mrow[r] - mn);
      mrow[r] = mn;
      float rs = 0.f;
      #pragma unroll
      for (int nf = 0; nf < 4; nf++) {
        float p = __expf(sc[nf][r] - mn);
        pv[nf][r] = p;
        rs += p;
      }
      rs += __shfl_xor(rs, 1);
      rs += __shfl_xor(rs, 2);
      rs += __shfl_xor(rs, 4);
      rs += __shfl_xor(rs, 8);
      lrow[r] = lrow[r] * al + rs;
      #pragma unroll
      for (int nf = 0; nf < 8; nf++) o[nf][r] *= al;
    }

    // P -> LDS (per-wave region), then PV
    #pragma unroll
    for (int nf = 0; nf < 4; nf++)
      #pragma unroll
      for (int r = 0; r < 4; r++)
        Pw[(g * 4 + r) * 72 + nf * 16 + c16] = f2bf(pv[nf][r]);
    __syncthreads();

    short8 pa[2];
    #pragma unroll
    for (int kf = 0; kf < 2; kf++)
      pa[kf] = *(const short8*)(Pw + c16 * 72 + kf * 32 + 8 * g);
    #pragma unroll
    for (int nf = 0; nf < 8; nf++)
      #pragma unroll
      for (int kf = 0; kf < 2; kf++) {
        short8 vb = *(const short8*)(Vs + (nf * 16 + c16) * 72 + kf * 32 + 8 * g);
        o[nf] = __builtin_amdgcn_mfma_f32_16x16x32_bf16(pa[kf], vb, o[nf], 0, 0, 0);
      }
  }

  float ri[4];
  #pragma unroll
  for (int r = 0; r < 4; r++) ri[r] = 1.0f / lrow[r];
  size_t yr0 = (size_t)(b * 2048 + qt * 64 + w * 16 + g * 4);
  #pragma unroll
  for (int nf = 0; nf < 8; nf++) {
    int col = h * 128 + nf * 16 + c16;
    #pragma unroll
    for (int r = 0; r < 4; r++)
      y[(yr0 + r) * 2048 + col] = f2bf(o[nf][r] * ri[r]);
  }
}

// ---------------------------------------------------------------------------
extern "C" void kernel_launch(void* const* d_in, const int* in_sizes, int n_in,
                              void* d_out, int out_size, void* d_ws, size_t ws_size,
                              hipStream_t stream) {
  (void)in_sizes; (void)n_in; (void)out_size; (void)ws_size;
  const float* x      = (const float*)d_in[0];
  const float* W_attn = (const float*)d_in[1];
  const float* b_attn = (const float*)d_in[2];
  const float* Aq     = (const float*)d_in[3];
  const float* Bq     = (const float*)d_in[4];
  const float* Ak     = (const float*)d_in[5];
  const float* Bk     = (const float*)d_in[6];
  const float* W_proj = (const float*)d_in[7];
  const float* b_proj = (const float*)d_in[8];

  char* ws = (char*)d_ws;
  short* xb  = (short*)(ws + 0);          // 8192x2048 bf16 (reused as y)
  short* WTa = (short*)(ws + 33554432);   // 6144x2048 bf16
  short* WTp = (short*)(ws + 58720256);   // 2048x2048 bf16
  short* qkv = (short*)(ws + 67108864);   // 8192x6144 bf16
  float* Tq  = (float*)(ws + 167772160);  // 8192x8 f32
  float* Tk  = (float*)(ws + 168034304);
  float* ct  = (float*)(ws + 168296448);  // 2048x64 f32
  float* st  = (float*)(ws + 168820736);
  short* vT  = (short*)(ws + 169345024);  // 64x128x2048 bf16  (end: 202899456)
  short* y   = xb;

  k_f2b<<<8192, 256, 0, stream>>>(x, xb, 2097152);
  k_wT<<<dim3(192, 64), dim3(32, 8), 0, stream>>>(W_attn, WTa, 2048, 6144);
  k_wT<<<dim3(64, 64), dim3(32, 8), 0, stream>>>(W_proj, WTp, 2048, 2048);
  k_ropetab<<<2048, 64, 0, stream>>>(ct, st);
  k_gemm<short><<<dim3(64, 48), 256, 0, stream>>>(xb, WTa, b_attn, qkv, 8192, 6144, 2048);
  k_lora_t<<<dim3(8192, 2), 256, 0, stream>>>(qkv, Aq, Ak, Tq, Tk);
  k_finalize<<<dim3(8192, 2), 256, 0, stream>>>(qkv, Tq, Tk, Bq, Bk, ct, st);
  k_vt<<<dim3(64, 4, 64), dim3(32, 8), 0, stream>>>(qkv, vT);
  k_attn<<<dim3(32, 64), 256, 0, stream>>>(qkv, vT, y);
  k_gemm<float><<<dim3(64, 16), 256, 0, stream>>>(y, WTp, b_proj, (float*)d_out, 8192, 2048, 2048);
}

// Round 2
// 868.008 us; speedup vs baseline: 1.0672x; 1.0672x over previous
//
#include <hip/hip_runtime.h>
#include <stdint.h>

// ---------------------------------------------------------------------------
// CausalSelfAttention with LoRA(Q,K) + RoPE, bf16 MFMA pipeline for gfx950.
// B=4, T=2048, C=2048, H=16, D=128, LORA_R=8.
// ---------------------------------------------------------------------------

typedef __attribute__((ext_vector_type(8))) short short8;
typedef __attribute__((ext_vector_type(4))) float floatx4;

__device__ __forceinline__ float bf2f(short h) {
  union { unsigned int u; float f; } v;
  v.u = ((unsigned int)(unsigned short)h) << 16;
  return v.f;
}
__device__ __forceinline__ short f2bf(float f) {
  unsigned int u = __float_as_uint(f);
  unsigned int r = (u + 0x7FFFu + ((u >> 16) & 1u)) >> 16;  // RNE
  return (short)r;
}

__device__ __forceinline__ void gload_lds16(const short* g, short* l) {
  __builtin_amdgcn_global_load_lds(
      (const __attribute__((address_space(1))) unsigned int*)g,
      (__attribute__((address_space(3))) unsigned int*)l, 16, 0, 0);
}

__device__ __forceinline__ void store_out(float* p, float v) { *p = v; }
__device__ __forceinline__ void store_out(short* p, float v) { *p = f2bf(v); }

// ---------------- fp32 -> bf16 convert (vectorized) ----------------
__global__ void k_f2b(const float* __restrict__ in, short* __restrict__ out, int n8) {
  int i = blockIdx.x * 256 + threadIdx.x;
  if (i >= n8) return;
  const float4* p = (const float4*)in + (size_t)i * 2;
  float4 a = p[0], b = p[1];
  short8 v;
  v[0] = f2bf(a.x); v[1] = f2bf(a.y); v[2] = f2bf(a.z); v[3] = f2bf(a.w);
  v[4] = f2bf(b.x); v[5] = f2bf(b.y); v[6] = f2bf(b.z); v[7] = f2bf(b.w);
  *(short8*)(out + (size_t)i * 8) = v;
}

// ---------------- W [K][N] fp32 -> WT [N][K] bf16 (tiled transpose) ----------------
__global__ void k_wT(const float* __restrict__ W, short* __restrict__ WT, int K, int N) {
  __shared__ float tile[32][33];
  int n0 = blockIdx.x * 32, k0 = blockIdx.y * 32;
  int tx = threadIdx.x, ty = threadIdx.y;  // (32,8)
  #pragma unroll
  for (int i = 0; i < 4; i++)
    tile[ty + i * 8][tx] = W[(size_t)(k0 + ty + i * 8) * N + n0 + tx];
  __syncthreads();
  #pragma unroll
  for (int i = 0; i < 4; i++)
    WT[(size_t)(n0 + ty + i * 8) * K + k0 + tx] = f2bf(tile[tx][ty + i * 8]);
}

// ---------------- RoPE cos/sin tables [2048][64] fp32 ----------------
__global__ void k_ropetab(float* __restrict__ ct, float* __restrict__ st) {
  int t = blockIdx.x, j = threadIdx.x;  // 64 threads
  float invf = powf(10000.0f, -(float)(2 * j) / 128.0f);
  float ang = (float)t * invf;
  ct[t * 64 + j] = cosf(ang);
  st[t * 64 + j] = sinf(ang);
}

// ---------------- bf16 MFMA GEMM: C[M][N] = A[M][K] @ BT[N][K]^T + bias ----------------
// 128x128 tile, BK=64, 4 waves, each wave 64x64 (4x4 frags of 16x16x32).
template <typename OutT>
__global__ __launch_bounds__(256, 2) void k_gemm(
    const short* __restrict__ A, const short* __restrict__ BT,
    const float* __restrict__ bias, OutT* __restrict__ C,
    int M, int N, int K)
{
  __shared__ __attribute__((aligned(16))) short As[128 * 64];
  __shared__ __attribute__((aligned(16))) short Bs[128 * 64];
  const int t = threadIdx.x;
  const int w = t >> 6, l = t & 63;
  const int g = l >> 4, c16 = l & 15;
  const int lr = l >> 3, lc8 = (l & 7) * 8;
  const int wr = w >> 1, wc = w & 1;
  const size_t bm = blockIdx.x, bn = blockIdx.y;

  floatx4 acc[4][4];
  #pragma unroll
  for (int m = 0; m < 4; m++)
    #pragma unroll
    for (int n = 0; n < 4; n++)
      acc[m][n] = (floatx4){0.f, 0.f, 0.f, 0.f};

  const short* Ablk = A + bm * 128 * (size_t)K;
  const short* Bblk = BT + bn * 128 * (size_t)K;

  for (int k0 = 0; k0 < K; k0 += 64) {
    #pragma unroll
    for (int i = 0; i < 4; i++) {
      int row = (i * 4 + w) * 8 + lr;  // per-wave-contiguous LDS chunks
      gload_lds16(Ablk + (size_t)row * K + k0 + lc8, As + row * 64 + lc8);
      gload_lds16(Bblk + (size_t)row * K + k0 + lc8, Bs + row * 64 + lc8);
    }
    __syncthreads();
    #pragma unroll
    for (int kk = 0; kk < 64; kk += 32) {
      short8 af[4], bfv[4];
      #pragma unroll
      for (int m = 0; m < 4; m++)
        af[m] = *(const short8*)(As + (wr * 64 + m * 16 + c16) * 64 + kk + 8 * g);
      #pragma unroll
      for (int n = 0; n < 4; n++)
        bfv[n] = *(const short8*)(Bs + (wc * 64 + n * 16 + c16) * 64 + kk + 8 * g);
      #pragma unroll
      for (int m = 0; m < 4; m++)
        #pragma unroll
        for (int n = 0; n < 4; n++)
          acc[m][n] = __builtin_amdgcn_mfma_f32_16x16x32_bf16(af[m], bfv[n], acc[m][n], 0, 0, 0);
    }
    __syncthreads();
  }

  #pragma unroll
  for (int m = 0; m < 4; m++) {
    #pragma unroll
    for (int n = 0; n < 4; n++) {
      int col = (int)bn * 128 + wc * 64 + n * 16 + c16;
      float bv = bias[col];
      #pragma unroll
      for (int r = 0; r < 4; r++) {
        size_t rowg = bm * 128 + (size_t)(wr * 64 + m * 16 + g * 4 + r);
        store_out(C + rowg * (size_t)N + col, acc[m][n][r] + bv);
      }
    }
  }
}

// ---------------- LoRA stage 1: T[row][8] = qkv_slice[row][:2048] @ A ----------------
__global__ __launch_bounds__(256) void k_lora_t(
    const short* __restrict__ qkv, const float* __restrict__ Aq,
    const float* __restrict__ Ak, float* __restrict__ Tq, float* __restrict__ Tk)
{
  const int row = blockIdx.x, which = blockIdx.y;
  const float* Am = which ? Ak : Aq;
  float* T = which ? Tk : Tq;
  const short* src = qkv + (size_t)row * 6144 + which * 2048;
  const int t = threadIdx.x;
  short8 q8 = *(const short8*)(src + t * 8);
  float acc[8];
  #pragma unroll
  for (int r = 0; r < 8; r++) acc[r] = 0.f;
  #pragma unroll
  for (int e = 0; e < 8; e++) {
    float qv = bf2f(q8[e]);
    const float* ar = Am + (size_t)(t * 8 + e) * 8;
    #pragma unroll
    for (int r = 0; r < 8; r++) acc[r] += qv * ar[r];
  }
  #pragma unroll
  for (int r = 0; r < 8; r++)
    for (int off = 32; off > 0; off >>= 1)
      acc[r] += __shfl_xor(acc[r], off);
  __shared__ float red[4][8];
  int w = t >> 6, l = t & 63;
  if (l == 0) {
    #pragma unroll
    for (int r = 0; r < 8; r++) red[w][r] = acc[r];
  }
  __syncthreads();
  if (t < 8)
    T[(size_t)row * 8 + t] = red[0][t] + red[1][t] + red[2][t] + red[3][t];
}

// lora'd value at column c of a 2048-wide q/k row
__device__ __forceinline__ float lval(const short* row, const float* Bm,
                                      const float* Tr, int c) {
  float v = bf2f(row[c]);
  #pragma unroll
  for (int r = 0; r < 8; r++) v += Tr[r] * Bm[r * 2048 + c];
  return v;
}

// ---------------- LoRA delta + RoPE (+1/sqrt(D) fold on q), in-place ----------------
__global__ __launch_bounds__(256) void k_finalize(
    short* __restrict__ qkv, const float* __restrict__ Tq, const float* __restrict__ Tk,
    const float* __restrict__ Bq, const float* __restrict__ Bk,
    const float* __restrict__ ct, const float* __restrict__ st)
{
  const int tok = blockIdx.x, which = blockIdx.y;
  const float* Bm = which ? Bk : Bq;
  const float* T = (which ? Tk : Tq) + (size_t)tok * 8;
  short* row = qkv + (size_t)tok * 6144 + which * 2048;
  const int trow = tok & 2047;
  float Tr[8];
  #pragma unroll
  for (int r = 0; r < 8; r++) Tr[r] = T[r] * 0.125f;  // LORA_SCALING = 1/8
  const float qs = which ? 1.0f : 0.08838834764831845f;  // 1/sqrt(128) folded into q
  const int tid = threadIdx.x;
  float o1[4], o2[4];
  #pragma unroll
  for (int i = 0; i < 4; i++) {
    int u = tid + i * 256;
    int h = u >> 6, j = u & 63;
    int base = h * 128;
    // rope: out[j] = q[j]*cos - q[2j+1]*sin ; out[j+64] = q[j+64]*cos + q[2j]*sin
    float qa = lval(row, Bm, Tr, base + j);
    float qb = lval(row, Bm, Tr, base + j + 64);
    float qe = lval(row, Bm, Tr, base + 2 * j);
    float qo = lval(row, Bm, Tr, base + 2 * j + 1);
    float c = ct[trow * 64 + j], s = st[trow * 64 + j];
    o1[i] = (qa * c - qo * s) * qs;
    o2[i] = (qb * c + qe * s) * qs;
  }
  __syncthreads();  // all reads complete before in-place writes
  #pragma unroll
  for (int i = 0; i < 4; i++) {
    int u = tid + i * 256;
    int h = u >> 6, j = u & 63;
    int base = h * 128;
    row[base + j] = f2bf(o1[i]);
    row[base + j + 64] = f2bf(o2[i]);
  }
}

// ---------------- V transpose: vT[bh][d][t] = qkv[b*2048+t][4096 + h*128 + d] ----------------
__global__ void k_vt(const short* __restrict__ qkv, short* __restrict__ vT) {
  __shared__ short tile[32][33];
  int bh = blockIdx.z, b = bh >> 4, h = bh & 15;
  int t0 = blockIdx.x * 32, d0 = blockIdx.y * 32;
  int tx = threadIdx.x, ty = threadIdx.y;  // (32,8)
  #pragma unroll
  for (int i = 0; i < 4; i++) {
    int tt = t0 + ty + i * 8;
    tile[ty + i * 8][tx] = qkv[(size_t)(b * 2048 + tt) * 6144 + 4096 + h * 128 + d0 + tx];
  }
  __syncthreads();
  #pragma unroll
  for (int i = 0; i < 4; i++) {
    int d = d0 + ty + i * 8;
    vT[((size_t)bh * 128 + d) * 2048 + t0 + tx] = tile[tx][ty + i * 8];
  }
}

// ---------------- causal flash attention v2 ----------------
// grid (T/128, B*H); block 256 = 4 waves, each wave owns 32 q-rows (2 m-frags).
// T14 async staging (reg double-duty), per-wave P region (no block barrier),
// T13 defer-max rescale.
__global__ __launch_bounds__(256, 2) void k_attn(
    const short* __restrict__ qkv, const short* __restrict__ vT, short* __restrict__ y)
{
  __shared__ __attribute__((aligned(16))) short Ks[64 * 136];     // K tile, pad 136
  __shared__ __attribute__((aligned(16))) short Vs[128 * 72];     // V^T tile, pad 72
  __shared__ __attribute__((aligned(16))) short Ps[4 * 32 * 72];  // per-wave P
  const int qt = blockIdx.x, bh = blockIdx.y, b = bh >> 4, h = bh & 15;
  const int t = threadIdx.x, w = t >> 6, l = t & 63, g = l >> 4, c16 = l & 15;

  // Q A-fragments: wave w rows qt*128 + w*32 + m*16 + c16
  short8 qf[2][4];
  #pragma unroll
  for (int m = 0; m < 2; m++) {
    size_t goff = (size_t)(b * 2048 + qt * 128 + w * 32 + m * 16 + c16) * 6144 + h * 128;
    #pragma unroll
    for (int kf = 0; kf < 4; kf++)
      qf[m][kf] = *(const short8*)(qkv + goff + kf * 32 + 8 * g);
  }

  floatx4 o[2][8];
  float mrow[2][4], lrow[2][4];
  #pragma unroll
  for (int m = 0; m < 2; m++) {
    #pragma unroll
    for (int nf = 0; nf < 8; nf++) o[m][nf] = (floatx4){0.f, 0.f, 0.f, 0.f};
    #pragma unroll
    for (int r = 0; r < 4; r++) { mrow[m][r] = -1e30f; lrow[m][r] = 0.f; }
  }

  const int skr = t >> 2, sc0 = (t & 3) * 32;   // K staging: row, col base
  const int svd = t >> 1, sv0 = (t & 1) * 32;   // V staging
  const short* kbase = qkv + (size_t)(b * 2048) * 6144 + 2048 + h * 128;
  const short* vbase = vT + (size_t)bh * 128 * 2048;
  short* Pw = Ps + w * (32 * 72);

  const int ntiles = 2 * qt + 2;

  // prologue: issue tile-0 loads into regs
  short8 kreg[4], vreg[4];
  #pragma unroll
  for (int ii = 0; ii < 4; ii++) {
    kreg[ii] = *(const short8*)(kbase + (size_t)skr * 6144 + sc0 + ii * 8);
    vreg[ii] = *(const short8*)(vbase + (size_t)svd * 2048 + sv0 + ii * 8);
  }

  for (int kt = 0; kt < ntiles; kt++) {
    __syncthreads();  // prior iter's LDS reads complete before overwrite
    #pragma unroll
    for (int ii = 0; ii < 4; ii++) {
      *(short8*)(Ks + skr * 136 + sc0 + ii * 8) = kreg[ii];
      *(short8*)(Vs + svd * 72 + sv0 + ii * 8) = vreg[ii];
    }
    __syncthreads();  // staged tile visible

    // T14: issue NEXT tile's global loads now; latency hides under compute.
    if (kt + 1 < ntiles) {
      #pragma unroll
      for (int ii = 0; ii < 4; ii++) {
        kreg[ii] = *(const short8*)(kbase + (size_t)((kt + 1) * 64 + skr) * 6144 + sc0 + ii * 8);
        vreg[ii] = *(const short8*)(vbase + (size_t)svd * 2048 + (kt + 1) * 64 + sv0 + ii * 8);
      }
    }

    // ---- QK^T: sc[m][nf] over 64 keys ----
    floatx4 sc[2][4];
    #pragma unroll
    for (int m = 0; m < 2; m++)
      #pragma unroll
      for (int nf = 0; nf < 4; nf++) sc[m][nf] = (floatx4){0.f, 0.f, 0.f, 0.f};
    #pragma unroll
    for (int kf = 0; kf < 4; kf++)
      #pragma unroll
      for (int nf = 0; nf < 4; nf++) {
        short8 kb = *(const short8*)(Ks + (nf * 16 + c16) * 136 + kf * 32 + 8 * g);
        sc[0][nf] = __builtin_amdgcn_mfma_f32_16x16x32_bf16(qf[0][kf], kb, sc[0][nf], 0, 0, 0);
        sc[1][nf] = __builtin_amdgcn_mfma_f32_16x16x32_bf16(qf[1][kf], kb, sc[1][nf], 0, 0, 0);
      }

    if (kt >= 2 * qt) {  // diagonal region: causal mask
      #pragma unroll
      for (int m = 0; m < 2; m++)
        #pragma unroll
        for (int nf = 0; nf < 4; nf++) {
          int key = kt * 64 + nf * 16 + c16;
          #pragma unroll
          for (int r = 0; r < 4; r++) {
            int qr = qt * 128 + w * 32 + m * 16 + g * 4 + r;
            if (key > qr) sc[m][nf][r] = -1e30f;
          }
        }
    }

    // ---- online softmax with defer-max (T13) ----
    float rmv[2][4];
    float need = -1e30f;
    #pragma unroll
    for (int m = 0; m < 2; m++)
      #pragma unroll
      for (int r = 0; r < 4; r++) {
        float rm = fmaxf(fmaxf(sc[m][0][r], sc[m][1][r]), fmaxf(sc[m][2][r], sc[m][3][r]));
        rm = fmaxf(rm, __shfl_xor(rm, 1));
        rm = fmaxf(rm, __shfl_xor(rm, 2));
        rm = fmaxf(rm, __shfl_xor(rm, 4));
        rm = fmaxf(rm, __shfl_xor(rm, 8));
        rmv[m][r] = rm;
        need = fmaxf(need, rm - mrow[m][r]);
      }
    if (!__all(need <= 8.0f)) {  // rescale only when the running max moved
      #pragma unroll
      for (int m = 0; m < 2; m++)
        #pragma unroll
        for (int r = 0; r < 4; r++) {
          float mn = fmaxf(mrow[m][r], rmv[m][r]);
          float al = __expf(mrow[m][r] - mn);
          mrow[m][r] = mn;
          lrow[m][r] *= al;
          #pragma unroll
          for (int nf = 0; nf < 8; nf++) o[m][nf] *= al;
        }
    }
    #pragma unroll
    for (int m = 0; m < 2; m++)
      #pragma unroll
      for (int r = 0; r < 4; r++) {
        float rs = 0.f;
        float pr[4];
        #pragma unroll
        for (int nf = 0; nf < 4; nf++) {
          float p = __expf(sc[m][nf][r] - mrow[m][r]);
          pr[nf] = p;
          rs += p;
        }
        rs += __shfl_xor(rs, 1);
        rs += __shfl_xor(rs, 2);
        rs += __shfl_xor(rs, 4);
        rs += __shfl_xor(rs, 8);
        lrow[m][r] += rs;
        #pragma unroll
        for (int nf = 0; nf < 4; nf++)
          Pw[(m * 16 + g * 4 + r) * 72 + nf * 16 + c16] = f2bf(pr[nf]);
      }

    // per-wave P region: in-wave fence instead of a block barrier
    asm volatile("s_waitcnt lgkmcnt(0)" ::: "memory");
    __builtin_amdgcn_sched_barrier(0);

    // ---- PV: o[m][nf] += P[m] @ V ----
    short8 pa[2][2];
    #pragma unroll
    for (int m = 0; m < 2; m++)
      #pragma unroll
      for (int kf = 0; kf < 2; kf++)
        pa[m][kf] = *(const short8*)(Pw + (m * 16 + c16) * 72 + kf * 32 + 8 * g);
    #pragma unroll
    for (int kf = 0; kf < 2; kf++)
      #pragma unroll
      for (int nf = 0; nf < 8; nf++) {
        short8 vb = *(const short8*)(Vs + (nf * 16 + c16) * 72 + kf * 32 + 8 * g);
        o[0][nf] = __builtin_amdgcn_mfma_f32_16x16x32_bf16(pa[0][kf], vb, o[0][nf], 0, 0, 0);
        o[1][nf] = __builtin_amdgcn_mfma_f32_16x16x32_bf16(pa[1][kf], vb, o[1][nf], 0, 0, 0);
      }
  }

  #pragma unroll
  for (int m = 0; m < 2; m++) {
    float ri[4];
    #pragma unroll
    for (int r = 0; r < 4; r++) ri[r] = 1.0f / lrow[m][r];
    size_t yr0 = (size_t)(b * 2048 + qt * 128 + w * 32 + m * 16 + g * 4);
    #pragma unroll
    for (int nf = 0; nf < 8; nf++) {
      int col = h * 128 + nf * 16 + c16;
      #pragma unroll
      for (int r = 0; r < 4; r++)
        y[(yr0 + r) * 2048 + col] = f2bf(o[m][nf][r] * ri[r]);
    }
  }
}

// ---------------------------------------------------------------------------
extern "C" void kernel_launch(void* const* d_in, const int* in_sizes, int n_in,
                              void* d_out, int out_size, void* d_ws, size_t ws_size,
                              hipStream_t stream) {
  (void)in_sizes; (void)n_in; (void)out_size; (void)ws_size;
  const float* x      = (const float*)d_in[0];
  const float* W_attn = (const float*)d_in[1];
  const float* b_attn = (const float*)d_in[2];
  const float* Aq     = (const float*)d_in[3];
  const float* Bq     = (const float*)d_in[4];
  const float* Ak     = (const float*)d_in[5];
  const float* Bk     = (const float*)d_in[6];
  const float* W_proj = (const float*)d_in[7];
  const float* b_proj = (const float*)d_in[8];

  char* ws = (char*)d_ws;
  short* xb  = (short*)(ws + 0);          // 8192x2048 bf16 (reused as y)
  short* WTa = (short*)(ws + 33554432);   // 6144x2048 bf16
  short* WTp = (short*)(ws + 58720256);   // 2048x2048 bf16
  short* qkv = (short*)(ws + 67108864);   // 8192x6144 bf16
  float* Tq  = (float*)(ws + 167772160);  // 8192x8 f32
  float* Tk  = (float*)(ws + 168034304);
  float* ct  = (float*)(ws + 168296448);  // 2048x64 f32
  float* st  = (float*)(ws + 168820736);
  short* vT  = (short*)(ws + 169345024);  // 64x128x2048 bf16  (end: 202899456)
  short* y   = xb;

  k_f2b<<<8192, 256, 0, stream>>>(x, xb, 2097152);
  k_wT<<<dim3(192, 64), dim3(32, 8), 0, stream>>>(W_attn, WTa, 2048, 6144);
  k_wT<<<dim3(64, 64), dim3(32, 8), 0, stream>>>(W_proj, WTp, 2048, 2048);
  k_ropetab<<<2048, 64, 0, stream>>>(ct, st);
  k_gemm<short><<<dim3(64, 48), 256, 0, stream>>>(xb, WTa, b_attn, qkv, 8192, 6144, 2048);
  k_lora_t<<<dim3(8192, 2), 256, 0, stream>>>(qkv, Aq, Ak, Tq, Tk);
  k_finalize<<<dim3(8192, 2), 256, 0, stream>>>(qkv, Tq, Tk, Bq, Bk, ct, st);
  k_vt<<<dim3(64, 4, 64), dim3(32, 8), 0, stream>>>(qkv, vT);
  k_attn<<<dim3(16, 64), 256, 0, stream>>>(qkv, vT, y);
  k_gemm<float><<<dim3(64, 16), 256, 0, stream>>>(y, WTp, b_proj, (float*)d_out, 8192, 2048, 2048);
}